// Round 1
// baseline (1027.495 us; speedup 1.0000x reference)
//
#include <hip/hip_runtime.h>

// Problem constants (from reference): z (16,4096,256) fp32, codebook (1024,256),
// cluster_size (1024,), embed_avg (1024,256). BS = 65536 rows, D = 256, K = 1024.
#define N_ROWS 65536
#define DIM    256
#define KCODES 1024

// ---------------------------------------------------------------------------
// Kernel 1: c_sq[k] = sum_d codebook[k][d]^2. One wave per code.
// ---------------------------------------------------------------------------
__global__ __launch_bounds__(64) void csq_kernel(const float* __restrict__ cb,
                                                 float* __restrict__ c_sq) {
    const int k = blockIdx.x;
    const int l = threadIdx.x;
    float4 v = reinterpret_cast<const float4*>(cb)[k * 64 + l];  // 64 lanes x 4 = 256
    float s = v.x * v.x + v.y * v.y + v.z * v.z + v.w * v.w;
#pragma unroll
    for (int m = 32; m >= 1; m >>= 1) s += __shfl_xor(s, m, 64);
    if (l == 0) c_sq[k] = s;
}

// ---------------------------------------------------------------------------
// Kernel 2: main — per 64-row tile: full distance scan over K=1024 codes with
// LDS-staged tiles, fused argmin, z_q_st write, and atomic segment-sum scatter.
// ---------------------------------------------------------------------------
__global__ __launch_bounds__(256) void vq_main(
    const float* __restrict__ z, const float* __restrict__ cb,
    const float* __restrict__ csq_g,
    float* __restrict__ out_zq, float* __restrict__ out_idx,
    float* __restrict__ sums, float* __restrict__ counts) {
    // LDA 260 (pad +4 floats): keeps 16B alignment, breaks stride-256 bank aliasing.
    __shared__ float zs[64 * 260];     // 66560 B
    __shared__ float bs[64 * 260];     // 66560 B
    __shared__ float csq_s[KCODES];    //  4096 B
    __shared__ int   best_s[64];       //   256 B   -> total ~137 KB (1 block/CU)

    const int t = threadIdx.x;
    const int tx = t & 15;             // code group: codes tx + 16*j
    const int ty = t >> 4;             // row group:  rows 4*ty + i
    const int row0 = blockIdx.x << 6;  // 64 rows per block

    // Stage c_sq into LDS (broadcast-read in epilogues).
#pragma unroll
    for (int i = 0; i < 4; ++i) csq_s[t + i * 256] = csq_g[t + i * 256];

    // Stage z tile: 64 rows x 256 = 4096 float4s, linear & coalesced.
    const float4* z4 = reinterpret_cast<const float4*>(z) + (size_t)row0 * 64;
#pragma unroll
    for (int i = 0; i < 16; ++i) {
        int f4 = t + i * 256;
        int r = f4 >> 6, c = (f4 & 63) << 2;
        float4 v = z4[f4];
        *reinterpret_cast<float4*>(&zs[r * 260 + c]) = v;
    }
    __syncthreads();

    float bval[4], zsq[4];
    int   bidx[4];
#pragma unroll
    for (int i = 0; i < 4; ++i) { bval[i] = 3.4e38f; bidx[i] = 0x7fffffff; zsq[i] = 0.0f; }

    const int rowOff0 = (4 * ty + 0) * 260;
    const int rowOff1 = (4 * ty + 1) * 260;
    const int rowOff2 = (4 * ty + 2) * 260;
    const int rowOff3 = (4 * ty + 3) * 260;
    const int colOff0 = (tx + 0)  * 260;
    const int colOff1 = (tx + 16) * 260;
    const int colOff2 = (tx + 32) * 260;
    const int colOff3 = (tx + 48) * 260;

    for (int ck = 0; ck < 16; ++ck) {
        if (ck > 0) __syncthreads();  // everyone done reading previous bs
        // Stage codebook chunk ck (codes ck*64 .. ck*64+63).
        const float4* cb4 = reinterpret_cast<const float4*>(cb) + ck * 4096;
#pragma unroll
        for (int i = 0; i < 16; ++i) {
            int f4 = t + i * 256;
            int r = f4 >> 6, c = (f4 & 63) << 2;
            float4 v = cb4[f4];
            *reinterpret_cast<float4*>(&bs[r * 260 + c]) = v;
        }
        __syncthreads();

        float dot[4][4];
#pragma unroll
        for (int i = 0; i < 4; ++i)
#pragma unroll
            for (int j = 0; j < 4; ++j) dot[i][j] = 0.0f;

        const bool withZsq = (ck == 0);
#pragma unroll 2
        for (int d = 0; d < DIM; d += 4) {
            float4 a0 = *reinterpret_cast<const float4*>(&zs[rowOff0 + d]);
            float4 a1 = *reinterpret_cast<const float4*>(&zs[rowOff1 + d]);
            float4 a2 = *reinterpret_cast<const float4*>(&zs[rowOff2 + d]);
            float4 a3 = *reinterpret_cast<const float4*>(&zs[rowOff3 + d]);
            float4 b0 = *reinterpret_cast<const float4*>(&bs[colOff0 + d]);
            float4 b1 = *reinterpret_cast<const float4*>(&bs[colOff1 + d]);
            float4 b2 = *reinterpret_cast<const float4*>(&bs[colOff2 + d]);
            float4 b3 = *reinterpret_cast<const float4*>(&bs[colOff3 + d]);
            float4 A[4] = {a0, a1, a2, a3};
            float4 B[4] = {b0, b1, b2, b3};
#pragma unroll
            for (int i = 0; i < 4; ++i)
#pragma unroll
                for (int j = 0; j < 4; ++j) {
                    dot[i][j] += A[i].x * B[j].x;
                    dot[i][j] += A[i].y * B[j].y;
                    dot[i][j] += A[i].z * B[j].z;
                    dot[i][j] += A[i].w * B[j].w;
                }
            if (withZsq) {
#pragma unroll
                for (int i = 0; i < 4; ++i) {
                    zsq[i] += A[i].x * A[i].x;
                    zsq[i] += A[i].y * A[i].y;
                    zsq[i] += A[i].z * A[i].z;
                    zsq[i] += A[i].w * A[i].w;
                }
            }
        }

        // Epilogue: distances + running argmin (first-index tie-break like jnp.argmin).
#pragma unroll
        for (int j = 0; j < 4; ++j) {
            int code = (ck << 6) + tx + (j << 4);
            float cs = csq_s[code];
#pragma unroll
            for (int i = 0; i < 4; ++i) {
                float dist = (zsq[i] + cs) - 2.0f * dot[i][j];
                if (dist < bval[i] || (dist == bval[i] && code < bidx[i])) {
                    bval[i] = dist;
                    bidx[i] = code;
                }
            }
        }
    }

    // Cross-thread argmin: butterfly over the 16 lanes sharing a row group.
#pragma unroll
    for (int m = 1; m <= 8; m <<= 1) {
#pragma unroll
        for (int i = 0; i < 4; ++i) {
            float ov = __shfl_xor(bval[i], m, 64);
            int   oi = __shfl_xor(bidx[i], m, 64);
            if (ov < bval[i] || (ov == bval[i] && oi < bidx[i])) {
                bval[i] = ov;
                bidx[i] = oi;
            }
        }
    }
    if (tx == 0) {
#pragma unroll
        for (int i = 0; i < 4; ++i) {
            int r = 4 * ty + i;
            best_s[r] = bidx[i];
            out_idx[row0 + r] = (float)bidx[i];  // indices stored as fp32 values
        }
    }
    __syncthreads();

    // Histogram counts: one atomic per row.
    if (t < 64) atomicAdd(&counts[best_s[t]], 1.0f);

    // z_q_st write + segment-sum scatter. t == dim index (256 threads).
#pragma unroll 1
    for (int r = 0; r < 64; ++r) {
        int bk = best_s[r];                 // LDS broadcast
        float zv = zs[r * 260 + t];
        float cv = cb[bk * 256 + t];        // L2-resident gather
        size_t o = (size_t)(row0 + r) * 256 + t;
        out_zq[o] = zv + (cv - zv);         // exact reference STE arithmetic
        atomicAdd(&sums[bk * 256 + t], zv);
    }
}

// ---------------------------------------------------------------------------
// Kernel 3: EMA update + codebook normalization.
// ---------------------------------------------------------------------------
__global__ __launch_bounds__(256) void ema_kernel(
    const float* __restrict__ cluster_size, const float* __restrict__ embed_avg,
    const float* __restrict__ sums, const float* __restrict__ counts,
    float* __restrict__ out_cb, float* __restrict__ out_cs, float* __restrict__ out_ea) {
    const int k = blockIdx.x, d = threadIdx.x;
    const float DEC = 0.99f;
    const float OM  = 1.0f - 0.99f;
    const float EPSV = 1e-5f;
    float ncs = cluster_size[k] * DEC + counts[k] * OM;
    int o = k * 256 + d;
    float nea = embed_avg[o] * DEC + sums[o] * OM;
    out_ea[o] = nea;
    out_cb[o] = nea / (ncs + EPSV);
    if (d == 0) out_cs[k] = ncs;
}

// ---------------------------------------------------------------------------
extern "C" void kernel_launch(void* const* d_in, const int* in_sizes, int n_in,
                              void* d_out, int out_size, void* d_ws, size_t ws_size,
                              hipStream_t stream) {
    const float* z            = (const float*)d_in[0];
    const float* cb           = (const float*)d_in[1];
    const float* cluster_size = (const float*)d_in[2];
    const float* embed_avg    = (const float*)d_in[3];

    // Outputs concatenated flat in reference return order (all read back as fp32).
    float* out_zq  = (float*)d_out;                       // 65536*256
    float* out_idx = out_zq + (size_t)N_ROWS * DIM;       // 65536
    float* out_cb  = out_idx + N_ROWS;                    // 1024*256
    float* out_cs  = out_cb + (size_t)KCODES * DIM;       // 1024
    float* out_ea  = out_cs + KCODES;                     // 1024*256

    // Workspace: sums (K*D) | counts (K) | c_sq (K)
    float* sums   = (float*)d_ws;
    float* counts = sums + (size_t)KCODES * DIM;
    float* csq    = counts + KCODES;

    hipMemsetAsync(d_ws, 0, (size_t)(KCODES * DIM + KCODES) * sizeof(float), stream);
    csq_kernel<<<KCODES, 64, 0, stream>>>(cb, csq);
    vq_main<<<N_ROWS / 64, 256, 0, stream>>>(z, cb, csq, out_zq, out_idx, sums, counts);
    ema_kernel<<<KCODES, 256, 0, stream>>>(cluster_size, embed_avg, sums, counts,
                                           out_cb, out_cs, out_ea);
}

// Round 3
// 398.162 us; speedup vs baseline: 2.5806x; 2.5806x over previous
//
#include <hip/hip_runtime.h>

#define N_ROWS 65536
#define DIM    256
#define KCODES 1024

typedef _Float16 h8 __attribute__((ext_vector_type(8)));
typedef _Float16 h4 __attribute__((ext_vector_type(4)));
typedef float    f4 __attribute__((ext_vector_type(4)));

// ---------------------------------------------------------------------------
// Kernel 1: codebook -> f16 hi/lo split + c_sq (fp32). One wave per code.
// ---------------------------------------------------------------------------
__global__ __launch_bounds__(64) void prep_kernel(const float* __restrict__ cb,
                                                  _Float16* __restrict__ cb_hi,
                                                  _Float16* __restrict__ cb_lo,
                                                  float* __restrict__ csq) {
    const int k = blockIdx.x;
    const int l = threadIdx.x;
    float4 v = reinterpret_cast<const float4*>(cb)[k * 64 + l];
    h4 hv, lv;
    hv[0] = (_Float16)v.x; lv[0] = (_Float16)(v.x - (float)hv[0]);
    hv[1] = (_Float16)v.y; lv[1] = (_Float16)(v.y - (float)hv[1]);
    hv[2] = (_Float16)v.z; lv[2] = (_Float16)(v.z - (float)hv[2]);
    hv[3] = (_Float16)v.w; lv[3] = (_Float16)(v.w - (float)hv[3]);
    *reinterpret_cast<h4*>(&cb_hi[k * 256 + l * 4]) = hv;
    *reinterpret_cast<h4*>(&cb_lo[k * 256 + l * 4]) = lv;
    float s = v.x * v.x + v.y * v.y + v.z * v.z + v.w * v.w;
#pragma unroll
    for (int m = 32; m >= 1; m >>= 1) s += __shfl_xor(s, m, 64);
    if (l == 0) csq[k] = s;
}

// ---------------------------------------------------------------------------
// Kernel 2: MFMA distance GEMM + fused argmin.
// Block: 512 threads (8 waves, 2x4), 128 rows resident (f16 hi/lo in LDS,
// XOR-swizzled). Loop over 8 code-tiles of 128; per tile 8 dim-chunks of 32.
// dist_rel = csq[code] - 2*dot  (z_sq dropped: constant per row).
// ---------------------------------------------------------------------------
__global__ __launch_bounds__(512, 2) void vq_gemm(
    const float* __restrict__ z, const _Float16* __restrict__ cb_hi,
    const _Float16* __restrict__ cb_lo, const float* __restrict__ csq_g,
    float* __restrict__ out_idx, int* __restrict__ idx_ws) {
    __shared__ _Float16 Ahi[128 * 256];   // 64 KB, swizzled
    __shared__ _Float16 Alo[128 * 256];   // 64 KB, swizzled
    __shared__ _Float16 Bhi[128 * 40];    // 10 KB, rows padded to 40 f16 (80 B)
    __shared__ _Float16 Blo[128 * 40];    // 10 KB
    __shared__ float red_val[128 * 4];    // 2 KB
    __shared__ int   red_idx[128 * 4];    // 2 KB   -> total 155648 B

    const int t = threadIdx.x;
    const int row0 = blockIdx.x << 7;     // 128 rows per block
    const int wave = t >> 6;
    const int wr = wave >> 2;             // 0..1 : row half (64 rows)
    const int wc = wave & 3;              // 0..3 : code quarter (32 codes)
    const int lane = t & 63;
    const int lm = lane & 15;
    const int lk = lane >> 4;             // 0..3 : k-subgroup (8 of 32)

    // ---- Stage A: z rows -> f16 hi/lo in LDS, swizzled (T2) --------------
    {
        const float4* z4 = reinterpret_cast<const float4*>(z) + (size_t)row0 * 64;
#pragma unroll
        for (int i = 0; i < 16; ++i) {
            int f = t + i * 512;          // 8192 float4s total
            int row = f >> 6, k4 = f & 63;
            float4 v = z4[f];
            h4 hv, lv;
            hv[0] = (_Float16)v.x; lv[0] = (_Float16)(v.x - (float)hv[0]);
            hv[1] = (_Float16)v.y; lv[1] = (_Float16)(v.y - (float)hv[1]);
            hv[2] = (_Float16)v.z; lv[2] = (_Float16)(v.z - (float)hv[2]);
            hv[3] = (_Float16)v.w; lv[3] = (_Float16)(v.w - (float)hv[3]);
            int idx = (row * 256 + k4 * 4) ^ ((row & 7) << 3);  // byte ^= (row&7)<<4
            *reinterpret_cast<h4*>(&Ahi[idx]) = hv;
            *reinterpret_cast<h4*>(&Alo[idx]) = lv;
        }
    }

    f4 acc[4][2];
    float bval[4][4];
    int   bidx[4][4];
#pragma unroll
    for (int m = 0; m < 4; ++m)
#pragma unroll
        for (int j = 0; j < 4; ++j) { bval[m][j] = 3.4e38f; bidx[m][j] = 0x7fffffff; }

    const f4 zacc = {0.0f, 0.0f, 0.0f, 0.0f};

    for (int ct = 0; ct < 8; ++ct) {
#pragma unroll
        for (int m = 0; m < 4; ++m)
#pragma unroll
            for (int n = 0; n < 2; ++n) acc[m][n] = zacc;

        for (int dc = 0; dc < 8; ++dc) {
            __syncthreads();  // previous compute done reading B (also covers A stage)
            {   // stage B chunk: codes ct*128..+128, dims dc*32..+32
                int code = t >> 2, dp = (t & 3) << 3;
                size_t g = (size_t)(ct * 128 + code) * 256 + dc * 32 + dp;
                *reinterpret_cast<h8*>(&Bhi[code * 40 + dp]) =
                    *reinterpret_cast<const h8*>(&cb_hi[g]);
                *reinterpret_cast<h8*>(&Blo[code * 40 + dp]) =
                    *reinterpret_cast<const h8*>(&cb_lo[g]);
            }
            __syncthreads();

            h8 ah[4], al[4], bh[2], bl[2];
#pragma unroll
            for (int m = 0; m < 4; ++m) {
                int row = wr * 64 + m * 16 + lm;
                int idx = (row * 256 + dc * 32 + lk * 8) ^ ((row & 7) << 3);
                ah[m] = *reinterpret_cast<const h8*>(&Ahi[idx]);
                al[m] = *reinterpret_cast<const h8*>(&Alo[idx]);
            }
#pragma unroll
            for (int n = 0; n < 2; ++n) {
                int code = wc * 32 + n * 16 + lm;
                int idx = code * 40 + lk * 8;
                bh[n] = *reinterpret_cast<const h8*>(&Bhi[idx]);
                bl[n] = *reinterpret_cast<const h8*>(&Blo[idx]);
            }
#pragma unroll
            for (int m = 0; m < 4; ++m)
#pragma unroll
                for (int n = 0; n < 2; ++n) {
                    acc[m][n] = __builtin_amdgcn_mfma_f32_16x16x32_f16(ah[m], bh[n], acc[m][n], 0, 0, 0);
                    acc[m][n] = __builtin_amdgcn_mfma_f32_16x16x32_f16(ah[m], bl[n], acc[m][n], 0, 0, 0);
                    acc[m][n] = __builtin_amdgcn_mfma_f32_16x16x32_f16(al[m], bh[n], acc[m][n], 0, 0, 0);
                }
        }

        // ---- epilogue: dist_rel + running argmin -------------------------
#pragma unroll
        for (int n = 0; n < 2; ++n) {
            int code = ct * 128 + wc * 32 + n * 16 + lm;
            float cs = csq_g[code];
#pragma unroll
            for (int m = 0; m < 4; ++m)
#pragma unroll
                for (int j = 0; j < 4; ++j) {
                    float d = cs - 2.0f * acc[m][n][j];
                    if (d < bval[m][j] || (d == bval[m][j] && code < bidx[m][j])) {
                        bval[m][j] = d;
                        bidx[m][j] = code;
                    }
                }
        }
    }

    // ---- argmin reduce: butterfly over the 16 col-lanes ------------------
#pragma unroll
    for (int s = 1; s <= 8; s <<= 1) {
#pragma unroll
        for (int m = 0; m < 4; ++m)
#pragma unroll
            for (int j = 0; j < 4; ++j) {
                float ov = __shfl_xor(bval[m][j], s, 64);
                int   oi = __shfl_xor(bidx[m][j], s, 64);
                if (ov < bval[m][j] || (ov == bval[m][j] && oi < bidx[m][j])) {
                    bval[m][j] = ov;
                    bidx[m][j] = oi;
                }
            }
    }
    if (lm == 0) {
#pragma unroll
        for (int m = 0; m < 4; ++m)
#pragma unroll
            for (int j = 0; j < 4; ++j) {
                int rl = wr * 64 + m * 16 + lk * 4 + j;
                red_val[rl * 4 + wc] = bval[m][j];
                red_idx[rl * 4 + wc] = bidx[m][j];
            }
    }
    __syncthreads();
    if (t < 128) {  // cross-wave (code-quarter) reduce
        float bv = red_val[t * 4];
        int   bi = red_idx[t * 4];
#pragma unroll
        for (int w = 1; w < 4; ++w) {
            float v = red_val[t * 4 + w];
            int   i2 = red_idx[t * 4 + w];
            if (v < bv || (v == bv && i2 < bi)) { bv = v; bi = i2; }
        }
        out_idx[row0 + t] = (float)bi;
        idx_ws[row0 + t] = bi;
    }
}

// ---------------------------------------------------------------------------
// Kernel 3: gather z_q + STE write + atomic segment-sum scatter.
// 2048 blocks x 256 threads, 32 rows each.
// ---------------------------------------------------------------------------
__global__ __launch_bounds__(256) void scatter_kernel(
    const float* __restrict__ z, const float* __restrict__ cb,
    const int* __restrict__ idx_ws, float* __restrict__ out_zq,
    float* __restrict__ sums, float* __restrict__ counts) {
    __shared__ int sidx[32];
    const int t = threadIdx.x;
    const int r0 = blockIdx.x << 5;
    if (t < 32) sidx[t] = idx_ws[r0 + t];
    __syncthreads();
#pragma unroll 1
    for (int r = 0; r < 32; ++r) {
        int bk = sidx[r];
        size_t o = (size_t)(r0 + r) * 256 + t;
        float zv = z[o];
        float cv = cb[bk * 256 + t];
        out_zq[o] = zv + (cv - zv);       // exact reference STE arithmetic
        atomicAdd(&sums[bk * 256 + t], zv);
    }
    if (t < 32) atomicAdd(&counts[sidx[t]], 1.0f);
}

// ---------------------------------------------------------------------------
// Kernel 4: EMA update + codebook normalization.
// ---------------------------------------------------------------------------
__global__ __launch_bounds__(256) void ema_kernel(
    const float* __restrict__ cluster_size, const float* __restrict__ embed_avg,
    const float* __restrict__ sums, const float* __restrict__ counts,
    float* __restrict__ out_cb, float* __restrict__ out_cs, float* __restrict__ out_ea) {
    const int k = blockIdx.x, d = threadIdx.x;
    const float DEC = 0.99f;
    const float OM = 1.0f - 0.99f;
    const float EPSV = 1e-5f;
    float ncs = cluster_size[k] * DEC + counts[k] * OM;
    int o = k * 256 + d;
    float nea = embed_avg[o] * DEC + sums[o] * OM;
    out_ea[o] = nea;
    out_cb[o] = nea / (ncs + EPSV);
    if (d == 0) out_cs[k] = ncs;
}

// ---------------------------------------------------------------------------
extern "C" void kernel_launch(void* const* d_in, const int* in_sizes, int n_in,
                              void* d_out, int out_size, void* d_ws, size_t ws_size,
                              hipStream_t stream) {
    const float* z            = (const float*)d_in[0];
    const float* cb           = (const float*)d_in[1];
    const float* cluster_size = (const float*)d_in[2];
    const float* embed_avg    = (const float*)d_in[3];

    float* out_zq  = (float*)d_out;                      // 65536*256
    float* out_idx = out_zq + (size_t)N_ROWS * DIM;      // 65536
    float* out_cb  = out_idx + N_ROWS;                   // 1024*256
    float* out_cs  = out_cb + (size_t)KCODES * DIM;      // 1024
    float* out_ea  = out_cs + KCODES;                    // 1024*256

    // ws layout: cb_hi (512KB) | cb_lo (512KB) | csq (4KB) | sums (1MB) |
    //            counts (4KB) | idx (256KB)   -> ~2.3 MB total
    char* w = (char*)d_ws;
    _Float16* cb_hi = (_Float16*)w;                       w += (size_t)KCODES * DIM * 2;
    _Float16* cb_lo = (_Float16*)w;                       w += (size_t)KCODES * DIM * 2;
    float* csq      = (float*)w;                          w += (size_t)KCODES * 4;
    float* sums     = (float*)w;                          w += (size_t)KCODES * DIM * 4;
    float* counts   = (float*)w;                          w += (size_t)KCODES * 4;
    int*   idx_ws   = (int*)w;

    hipMemsetAsync(sums, 0, (size_t)(KCODES * DIM + KCODES) * sizeof(float), stream);
    prep_kernel<<<KCODES, 64, 0, stream>>>(cb, cb_hi, cb_lo, csq);
    vq_gemm<<<N_ROWS / 128, 512, 0, stream>>>(z, cb_hi, cb_lo, csq, out_idx, idx_ws);
    scatter_kernel<<<N_ROWS / 32, 256, 0, stream>>>(z, cb, idx_ws, out_zq, sums, counts);
    ema_kernel<<<KCODES, 256, 0, stream>>>(cluster_size, embed_avg, sums, counts,
                                           out_cb, out_cs, out_ea);
}